// Round 3
// baseline (29444.135 us; speedup 1.0000x reference)
//
#include <hip/hip_runtime.h>
#include <hip/hip_bf16.h>

#define B_  32
#define TS_ 64
#define TD_ 63
#define E_  256
#define U_  1024
#define G_  4096   // 4*U
#define VT_ 32000
#define NB_ 512    // persistent grid blocks (2 per CU)

typedef __attribute__((ext_vector_type(8))) short short8;
typedef __attribute__((ext_vector_type(4))) float floatx4;

__device__ __forceinline__ float sigf(float x){ return 1.0f/(1.0f+__expf(-x)); }
__device__ __forceinline__ float tanh_fast(float x){ return 2.0f/(1.0f+__expf(-2.0f*x)) - 1.0f; }
__device__ __forceinline__ unsigned short f2bf(float x){
  unsigned u = __float_as_uint(x);
  u += 0x7FFFu + ((u>>16)&1u);
  return (unsigned short)(u>>16);
}

// write-through store (agent scope -> past XCD L2 to coherence point)
__device__ __forceinline__ void st_wt(float* p, float v){
  __hip_atomic_store(p, v, __ATOMIC_RELAXED, __HIP_MEMORY_SCOPE_AGENT);
}

// ---------------- cache-neutral grid barrier ----------------
// Monotonic two-level counter, relaxed agent atomics only: no fences, no
// L2 invalidate -> weights stay L2-resident across steps. Data visibility:
// producers' write-through stores are drained by the s_waitcnt vmcnt(0)
// that precedes s_barrier (__syncthreads) before tid0 arrives.
__device__ __forceinline__ void gbar_sync(unsigned* bar, unsigned n){
  asm volatile("s_waitcnt vmcnt(0)" ::: "memory");
  __syncthreads();
  if(threadIdx.x==0){
    int g = blockIdx.x >> 4;   // 32 groups of 16 blocks
    unsigned v = __hip_atomic_fetch_add(bar + g*32, 1u, __ATOMIC_RELAXED, __HIP_MEMORY_SCOPE_AGENT);
    if((v & 15u) == 15u){
      unsigned r = __hip_atomic_fetch_add(bar + 1024, 1u, __ATOMIC_RELAXED, __HIP_MEMORY_SCOPE_AGENT);
      if((r & 31u) == 31u)
        __hip_atomic_store(bar + 1056, n, __ATOMIC_RELAXED, __HIP_MEMORY_SCOPE_AGENT);
    }
    while(__hip_atomic_load(bar + 1056, __ATOMIC_RELAXED, __HIP_MEMORY_SCOPE_AGENT) < n)
      __builtin_amdgcn_s_sleep(1);
  }
  __syncthreads();
  asm volatile("" ::: "memory");
}

// ---------------- zero init ----------------
__global__ void zero_kernel(float4* __restrict__ p, int n4){
  int i = blockIdx.x*256 + threadIdx.x;
  if(i < n4) p[i] = make_float4(0.f,0.f,0.f,0.f);
}

// ---------------- generic row-gather GEMM (fp32) ----------------
__global__ __launch_bounds__(256) void gemm_rows(
    const float* __restrict__ Atab, const int* __restrict__ tokens, int T,
    const float* __restrict__ Bw, const float* __restrict__ bias,
    float* __restrict__ C, int N, int K)
{
  __shared__ float as[64*20];
  int tid = threadIdx.x;
  int n  = blockIdx.x*256 + tid;
  int m0 = blockIdx.y*16;
  float acc[16];
  #pragma unroll
  for(int r=0;r<16;r++) acc[r]=0.f;

  for(int kc=0; kc<K; kc+=64){
    __syncthreads();
    for(int i=tid; i<16*64; i+=256){
      int mm = i>>6, kk = i&63;
      int m = m0 + mm;
      const float* arow;
      if(tokens){
        int b = m & 31, t = m >> 5;
        arow = Atab + (size_t)tokens[b*T + t]*K;
      } else {
        arow = Atab + (size_t)m*K;
      }
      as[kk*20 + mm] = arow[kc + kk];
    }
    __syncthreads();
    for(int kk=0; kk<64; kk++){
      float bv = Bw[(size_t)(kc+kk)*N + n];
      const float4* ap = (const float4*)(as + kk*20);
      float4 a0 = ap[0], a1 = ap[1], a2 = ap[2], a3 = ap[3];
      acc[0]  += a0.x*bv; acc[1]  += a0.y*bv; acc[2]  += a0.z*bv; acc[3]  += a0.w*bv;
      acc[4]  += a1.x*bv; acc[5]  += a1.y*bv; acc[6]  += a1.z*bv; acc[7]  += a1.w*bv;
      acc[8]  += a2.x*bv; acc[9]  += a2.y*bv; acc[10] += a2.z*bv; acc[11] += a2.w*bv;
      acc[12] += a3.x*bv; acc[13] += a3.y*bv; acc[14] += a3.z*bv; acc[15] += a3.w*bv;
    }
  }
  float bv = bias ? bias[n] : 0.f;
  #pragma unroll
  for(int r=0;r<16;r++)
    C[(size_t)(m0+r)*N + n] = acc[r] + bv;
}

// ---------------- f32 transpose: dst[n][dstOff+k] = src[k][n] ----------------
__global__ __launch_bounds__(256) void transpose_f32(
    const float* __restrict__ src, float* __restrict__ dst,
    int N, int dstStride, int dstOff)
{
  __shared__ float tle[32][33];
  int n0 = blockIdx.x*32, k0 = blockIdx.y*32;
  int tid = threadIdx.x, cx = tid&31, ry = tid>>5;
  for(int r=ry; r<32; r+=8) tle[r][cx] = src[(size_t)(k0+r)*N + n0+cx];
  __syncthreads();
  for(int r=ry; r<32; r+=8)
    dst[(size_t)(n0+r)*dstStride + dstOff + k0+cx] = tle[cx][r];
}

// ================= persistent encoder =================
// 512 blocks: bid -> x=bid&7 (XCD), j=bid>>3; cg=x*16+(j>>2) (0..127 col-group,
// u0=cg*8), bq=j&3 (8-batch slice). Thread: 1 full-K dot (b, col) of
// z = h_prev @ Wh_e (WheT pre-transposed [4096][1024]). Gates on tid<64;
// cell state c lives in a register across all 64 steps. h written
// write-through into memory[t] (rotating -> readers never see stale lines).
struct EncP {
  const float* WheT; const float* Xe; const float* zeros;
  float* memory; float* cst; unsigned* bar;
};
__global__ __launch_bounds__(256, 2) void enc_rnn(EncP P)
{
  const int bid = blockIdx.x, tid = threadIdx.x;
  const int x = bid & 7, j = bid >> 3;
  const int cg = x*16 + (j>>2), bq = j & 3;
  const int u0 = cg*8;
  const int bL = tid & 7, lc = tid >> 3;
  const int b  = bq*8 + bL;
  const int col = (lc>>3)*U_ + u0 + (lc&7);
  const float4* wrow = (const float4*)(P.WheT + (size_t)col*U_);
  const int gb = tid & 7, gu = tid >> 3;      // valid for tid<64
  const int gB = bq*8 + gb, gU = u0 + gu;
  __shared__ float zs[32][8];
  float c_reg = 0.f;
  unsigned bc = 0;

  for(int t=0; t<TS_; t++){
    const float* hsrc = t ? (P.memory + (size_t)(t-1)*B_*U_) : P.zeros;
    const float4* hv = (const float4*)(hsrc + (size_t)b*U_);
    float acc = 0.f;
    #pragma unroll 8
    for(int k=0; k<U_/4; k++){
      float4 h4 = hv[k], w4 = wrow[k];
      acc += h4.x*w4.x + h4.y*w4.y + h4.z*w4.z + h4.w*w4.w;
    }
    zs[lc][bL] = acc;
    __syncthreads();
    if(tid < 64){
      const float* Xt = P.Xe + (size_t)t*B_*G_ + (size_t)gB*G_;
      float zi = Xt[gU]        + zs[gu][gb];
      float zf = Xt[U_+gU]     + zs[8+gu][gb];
      float zg = Xt[2*U_+gU]   + zs[16+gu][gb];
      float zo = Xt[3*U_+gU]   + zs[24+gu][gb];
      float cn = sigf(zf)*c_reg + sigf(zi)*tanh_fast(zg);
      float hn = sigf(zo)*tanh_fast(cn);
      c_reg = cn;
      st_wt(P.memory + (size_t)t*B_*U_ + (size_t)gB*U_ + gU, hn);
    }
    gbar_sync(P.bar, ++bc);
  }
  if(tid < 64) P.cst[(size_t)gB*U_ + gU] = c_reg;   // flushed at kernel end
}

// ================= persistent decoder =================
// Per step: P1 z-GEMV (K=2048 over [h|a], WdT [4096][2048]) + gates -> hdec[t];
// P2 (blocks 0..31, one per b): scores/softmax/ctx -> ctxb[t];
// P3 a-proj (K=2048 over [h|ctx], WaT [1024][2048], 4-lane split-K) ->
// attn[t+1] + bf16 emit. 3 cache-neutral barriers/step.
struct DecP {
  const float* WdT; const float* WaT; const float* Xd;
  const float* keys; const float* memory; const float* h_enc;
  float* hdec; float* ctxb; float* attn; const float* cst;
  unsigned short* attn_bf; unsigned* bar;
};
__global__ __launch_bounds__(256, 2) void dec_rnn(DecP P)
{
  const int bid = blockIdx.x, tid = threadIdx.x;
  const int x = bid & 7, j = bid >> 3;
  const int cg = x*16 + (j>>2), bq = j & 3;
  const int u0 = cg*8;
  const int bL = tid & 7, lc = tid >> 3;
  const int b  = bq*8 + bL;
  const int col = (lc>>3)*U_ + u0 + (lc&7);
  const float4* wrow = (const float4*)(P.WdT + (size_t)col*2048);
  const int gb = tid & 7, gu = tid >> 3;
  const int gB = bq*8 + gb, gU = u0 + gu;
  // P3 mapping: 64 dots (8 b x 8 cols), 4 lanes split-K each
  const int d3 = tid >> 2, part = tid & 3;
  const int b3 = bq*8 + (d3 & 7), c3 = cg*8 + (d3 >> 3);
  const float4* warow = (const float4*)(P.WaT + (size_t)c3*2048);
  __shared__ float zs[32][8];
  __shared__ float hs[1024];
  __shared__ float sc[64];
  __shared__ float al[64];
  float c_reg = 0.f;
  if(tid < 64) c_reg = P.cst[(size_t)gB*U_ + gU];
  unsigned bc = 0;

  for(int t=0; t<TD_; t++){
    { // ---- P1: z = [h_prev | a_prev] @ Wd, gates ----
      const float* hsrc = t ? (P.hdec + (size_t)(t-1)*B_*U_) : P.h_enc;
      const float* asrc = P.attn + (size_t)t*B_*U_;
      const float4* hv = (const float4*)(hsrc + (size_t)b*U_);
      const float4* av = (const float4*)(asrc + (size_t)b*U_);
      float acc = 0.f;
      #pragma unroll 8
      for(int k=0; k<256; k++){
        float4 h4 = hv[k], w4 = wrow[k];
        acc += h4.x*w4.x + h4.y*w4.y + h4.z*w4.z + h4.w*w4.w;
      }
      #pragma unroll 8
      for(int k=0; k<256; k++){
        float4 a4 = av[k], w4 = wrow[256+k];
        acc += a4.x*w4.x + a4.y*w4.y + a4.z*w4.z + a4.w*w4.w;
      }
      zs[lc][bL] = acc;
      __syncthreads();
      if(tid < 64){
        const float* Xt = P.Xd + (size_t)t*B_*G_ + (size_t)gB*G_;
        float zi = Xt[gU]        + zs[gu][gb];
        float zf = Xt[U_+gU]     + zs[8+gu][gb];
        float zg = Xt[2*U_+gU]   + zs[16+gu][gb];
        float zo = Xt[3*U_+gU]   + zs[24+gu][gb];
        float cn = sigf(zf)*c_reg + sigf(zi)*tanh_fast(zg);
        float hn = sigf(zo)*tanh_fast(cn);
        c_reg = cn;
        st_wt(P.hdec + (size_t)t*B_*U_ + (size_t)gB*U_ + gU, hn);
      }
    }
    gbar_sync(P.bar, ++bc);
    // ---- P2: attention (one block per batch) ----
    if(bid < B_){
      const int bb = bid;
      const float* hrow = P.hdec + (size_t)t*B_*U_ + (size_t)bb*U_;
      for(int i=tid; i<1024; i+=256) hs[i] = hrow[i];
      __syncthreads();
      int w = tid>>6, ln = tid&63;
      for(int si=0; si<16; si++){
        int s = w*16 + si;
        const float* kr = P.keys + ((size_t)s*B_ + bb)*U_;
        float p = 0.f;
        for(int kk=ln; kk<1024; kk+=64) p += hs[kk]*kr[kk];
        #pragma unroll
        for(int off=32; off; off>>=1) p += __shfl_down(p, off);
        if(ln==0) sc[s] = p;
      }
      __syncthreads();
      if(tid < 64){
        float v = sc[tid], mx = v;
        #pragma unroll
        for(int off=32; off; off>>=1) mx = fmaxf(mx, __shfl_down(mx, off));
        mx = __shfl(mx, 0);
        float e = __expf(v - mx), sm = e;
        #pragma unroll
        for(int off=32; off; off>>=1) sm += __shfl_down(sm, off);
        sm = __shfl(sm, 0);
        al[tid] = e/sm;
      }
      __syncthreads();
      #pragma unroll
      for(int uu=0; uu<4; uu++){
        int u = uu*256 + tid;
        float a = 0.f;
        for(int s=0; s<64; s++) a += al[s]*P.memory[((size_t)s*B_ + bb)*U_ + u];
        st_wt(P.ctxb + (size_t)t*B_*U_ + (size_t)bb*U_ + u, a);
      }
    }
    gbar_sync(P.bar, ++bc);
    { // ---- P3: a = [h | ctx] @ Wa ----
      const float* hsrc = P.hdec + (size_t)t*B_*U_ + (size_t)b3*U_;
      const float* csrc = P.ctxb + (size_t)t*B_*U_ + (size_t)b3*U_;
      const float4* sv = (part < 2) ? (const float4*)hsrc : (const float4*)csrc;
      const int sbase = (part & 1)*128;
      const float4* wv = warow + part*128;
      float acc = 0.f;
      #pragma unroll 8
      for(int i=0; i<128; i++){
        float4 s4 = sv[sbase+i], w4 = wv[i];
        acc += s4.x*w4.x + s4.y*w4.y + s4.z*w4.z + s4.w*w4.w;
      }
      acc += __shfl_xor(acc, 1);
      acc += __shfl_xor(acc, 2);
      if(part == 0){
        st_wt(P.attn + (size_t)(t+1)*B_*U_ + (size_t)b3*U_ + c3, acc);
        P.attn_bf[(size_t)t*B_*U_ + (size_t)b3*U_ + c3] = f2bf(acc);
      }
    }
    gbar_sync(P.bar, ++bc);
  }
}

// ---------------- (fallback) recurrent-step split-K GEMM ----------------
__global__ __launch_bounds__(256) void step_mm(
    const float* __restrict__ W1, const float* __restrict__ W2,
    const float* __restrict__ s1, const float* __restrict__ s2,
    float* __restrict__ zpart, int N, int HQ)
{
  int tid = threadIdx.x;
  int lane = tid & 63, mg = tid >> 6;
  int n = blockIdx.x*64 + lane;
  int kq = blockIdx.y;
  const float* W;
  const float* hp;
  if(kq < HQ){
    int k0 = kq*128;
    W  = W1 + (size_t)k0*N + n;
    hp = s1 + (size_t)(mg*8)*U_ + k0;
  } else {
    int k0 = (kq-HQ)*128;
    W  = W2 + (size_t)k0*N + n;
    hp = s2 + (size_t)(mg*8)*U_ + k0;
  }
  float acc[8];
  #pragma unroll
  for(int i=0;i<8;i++) acc[i]=0.f;
  for(int kk=0; kk<128; kk+=16){
    float w[16];
    #pragma unroll
    for(int jj=0;jj<16;jj++) w[jj] = W[(size_t)(kk+jj)*N];
    #pragma unroll
    for(int mi=0; mi<8; mi++){
      const float4* h4 = (const float4*)(hp + (size_t)mi*U_ + kk);
      float4 ha = h4[0], hb = h4[1], hc = h4[2], hd = h4[3];
      acc[mi] += ha.x*w[0]  + ha.y*w[1]  + ha.z*w[2]  + ha.w*w[3]
               + hb.x*w[4]  + hb.y*w[5]  + hb.z*w[6]  + hb.w*w[7]
               + hc.x*w[8]  + hc.y*w[9]  + hc.z*w[10] + hc.w*w[11]
               + hd.x*w[12] + hd.y*w[13] + hd.z*w[14] + hd.w*w[15];
    }
  }
  float* zp = zpart + ((size_t)(kq*32 + mg*8)) * N + n;
  #pragma unroll
  for(int mi=0; mi<8; mi++)
    zp[(size_t)mi * N] = acc[mi];
}

// ---------------- (fallback) gates ----------------
__global__ __launch_bounds__(256) void gate_h(
    const float* __restrict__ X_t, const float* __restrict__ zpart, int KQ,
    float* __restrict__ c, float* __restrict__ hout)
{
  int i = blockIdx.x*256 + threadIdx.x;
  int b = i >> 10, u = i & 1023;
  float zg[4];
  #pragma unroll
  for(int g=0; g<4; g++){
    int col = g*U_ + u;
    float s = X_t[(size_t)b*G_ + col];
    for(int p=0; p<KQ; p++) s += zpart[((size_t)(p*32+b))*G_ + col];
    zg[g] = s;
  }
  float cn = sigf(zg[1])*c[i] + sigf(zg[0])*tanh_fast(zg[2]);
  float hn = sigf(zg[3])*tanh_fast(cn);
  c[i] = cn;
  hout[i] = hn;
}

// ---------------- (fallback) decoder gates+attention ----------------
__global__ __launch_bounds__(256) void dec_gate_attn(
    const float* __restrict__ Xd_t, const float* __restrict__ zpart,
    float* __restrict__ c, const float* __restrict__ keys,
    const float* __restrict__ memory, float* __restrict__ hout,
    float* __restrict__ ctx)
{
  int b = blockIdx.x;
  int tid = threadIdx.x;
  __shared__ float hs[1024];
  __shared__ float sc[64];
  __shared__ float al[64];
  #pragma unroll
  for(int uu=0; uu<4; uu++){
    int u = uu*256 + tid;
    float zg[4];
    #pragma unroll
    for(int g=0; g<4; g++){
      int col = g*U_ + u;
      float s = Xd_t[(size_t)b*G_ + col];
      #pragma unroll
      for(int p=0; p<16; p++) s += zpart[((size_t)(p*32+b))*G_ + col];
      zg[g] = s;
    }
    int ci = b*U_ + u;
    float cn = sigf(zg[1])*c[ci] + sigf(zg[0])*tanh_fast(zg[2]);
    float hn = sigf(zg[3])*tanh_fast(cn);
    c[ci] = cn;
    hs[u] = hn;
    hout[ci] = hn;
  }
  __syncthreads();
  int w = tid>>6, lane = tid&63;
  for(int si=0; si<16; si++){
    int s = w*16 + si;
    const float* kr = keys + ((size_t)s*B_ + b)*U_;
    float p = 0.f;
    for(int kk=lane; kk<1024; kk+=64) p += hs[kk]*kr[kk];
    for(int off=32; off; off>>=1) p += __shfl_down(p, off);
    if(lane==0) sc[s] = p;
  }
  __syncthreads();
  if(tid<64){
    float v = sc[tid];
    float mx = v;
    for(int off=32; off; off>>=1) mx = fmaxf(mx, __shfl_down(mx, off));
    mx = __shfl(mx, 0);
    float e = __expf(v - mx);
    float sm = e;
    for(int off=32; off; off>>=1) sm += __shfl_down(sm, off);
    sm = __shfl(sm, 0);
    al[tid] = e/sm;
  }
  __syncthreads();
  #pragma unroll
  for(int uu=0; uu<4; uu++){
    int u = uu*256 + tid;
    float a = 0.f;
    for(int s=0; s<64; s++) a += al[s]*memory[((size_t)s*B_ + b)*U_ + u];
    ctx[b*U_ + u] = a;
  }
}

// ---------------- (fallback) attention-projection combine ----------------
__global__ __launch_bounds__(256) void attn_combine(
    const float* __restrict__ apart, float* __restrict__ attn_next,
    unsigned short* __restrict__ abf)
{
  int i = blockIdx.x*256 + threadIdx.x;
  float s = 0.f;
  #pragma unroll
  for(int p=0; p<16; p++) s += apart[(size_t)p*32768 + i];
  attn_next[i] = s;
  abf[i] = f2bf(s);
}

// Wf [1024][32000] f32 -> WfT [32000][1024] bf16
__global__ __launch_bounds__(256) void transpose_f2bf(
    const float* __restrict__ Wf, unsigned short* __restrict__ WfT)
{
  __shared__ float t[32][33];
  int n0 = blockIdx.x*32, k0 = blockIdx.y*32;
  int tid = threadIdx.x;
  int cx = tid&31, ry = tid>>5;
  for(int r=ry; r<32; r+=8) t[r][cx] = Wf[(size_t)(k0+r)*VT_ + n0+cx];
  __syncthreads();
  for(int r=ry; r<32; r+=8)
    WfT[(size_t)(n0+r)*1024 + k0+cx] = f2bf(t[cx][r]);
}

// ---------------- logits GEMM: bf16 MFMA 16x16x32 ----------------
__global__ __launch_bounds__(256) void logits_gemm(
    const unsigned short* __restrict__ Abf, const unsigned short* __restrict__ Bt,
    const float* __restrict__ bias, float* __restrict__ out)
{
  __shared__ __align__(16) unsigned short As[32][40];
  __shared__ __align__(16) unsigned short Bs[256][40];
  int tid = threadIdx.x;
  int m0 = blockIdx.x*32, n0 = blockIdx.y*256;
  int w = tid>>6, lane = tid&63;
  int wm = w&1, wn = w>>1;
  floatx4 acc[8];
  #pragma unroll
  for(int i=0;i<8;i++) acc[i] = (floatx4)(0.f);

  int rl = lane&15, kg = lane>>4;

  for(int kt=0; kt<1024; kt+=32){
    __syncthreads();
    {
      int mm = tid>>3, kq = tid&7;
      const unsigned short* src = Abf + (size_t)(m0+mm)*1024 + kt + kq*4;
      *(uint2*)(&As[mm][kq*4]) = *(const uint2*)src;
    }
    {
      const unsigned short* bsrc = Bt + (size_t)(n0+tid)*1024 + kt;
      *(uint4*)(&Bs[tid][0])  = *(const uint4*)(bsrc);
      *(uint4*)(&Bs[tid][8])  = *(const uint4*)(bsrc+8);
      *(uint4*)(&Bs[tid][16]) = *(const uint4*)(bsrc+16);
      *(uint4*)(&Bs[tid][24]) = *(const uint4*)(bsrc+24);
    }
    __syncthreads();
    short8 afrag = *(const short8*)(&As[wm*16 + rl][kg*8]);
    #pragma unroll
    for(int nt=0; nt<8; nt++){
      short8 bfrag = *(const short8*)(&Bs[wn*128 + nt*16 + rl][kg*8]);
      acc[nt] = __builtin_amdgcn_mfma_f32_16x16x32_bf16(afrag, bfrag, acc[nt], 0,0,0);
    }
  }
  #pragma unroll
  for(int nt=0; nt<8; nt++){
    int n = n0 + wn*128 + nt*16 + rl;
    float bv = bias[n];
    #pragma unroll
    for(int r=0;r<4;r++){
      int m = m0 + wm*16 + kg*4 + r;
      int t = m>>5, b = m&31;
      out[((size_t)(b*TD_) + t)*VT_ + n] = acc[nt][r] + bv;
    }
  }
}

// ---------------- host ----------------
extern "C" void kernel_launch(void* const* d_in, const int* in_sizes, int n_in,
                              void* d_out, int out_size, void* d_ws, size_t ws_size,
                              hipStream_t stream) {
  (void)in_sizes; (void)n_in; (void)out_size;
  const int*   enc_in  = (const int*)d_in[0];
  const int*   dec_in  = (const int*)d_in[1];
  const float* enc_emb = (const float*)d_in[2];
  const float* dec_emb = (const float*)d_in[3];
  const float* Wx_e    = (const float*)d_in[4];
  const float* Wh_e    = (const float*)d_in[5];
  const float* b_e     = (const float*)d_in[6];
  const float* Wx_d    = (const float*)d_in[7];
  const float* Wh_d    = (const float*)d_in[8];
  const float* b_d     = (const float*)d_in[9];
  const float* Wm      = (const float*)d_in[10];
  const float* Wa      = (const float*)d_in[11];
  const float* Wf      = (const float*)d_in[12];
  const float* bf      = (const float*)d_in[13];
  float* out = (float*)d_out;

  float* ws = (float*)d_ws;
  size_t off = 0;
  // ---- prefix (shared with fallback) ----
  float* Xe       = ws + off; off += (size_t)TS_*B_*G_;     // 8388608
  float* Xd       = ws + off; off += (size_t)TD_*B_*G_;     // 8257536
  float* memory   = ws + off; off += (size_t)TS_*B_*U_;     // 2097152
  float* keys     = ws + off; off += (size_t)TS_*B_*U_;     // 2097152
  float* attn_buf = ws + off; off += (size_t)64*B_*U_;      // slot0 = zeros
  float* cst      = ws + off; off += (size_t)B_*U_;         // c (coop) / cbuf (fb)
  float* hbuf     = ws + off; off += (size_t)B_*U_;         // fallback
  float* ctxs     = ws + off; off += (size_t)B_*U_;         // fallback
  float* zpart    = ws + off; off += (size_t)16*B_*G_;      // fallback
  float* apart    = ws + off; off += (size_t)16*B_*U_;      // fallback
  unsigned short* attn_bf = (unsigned short*)(ws + off); off += (size_t)(2016*1024)/2;
  unsigned short* WfT     = (unsigned short*)(ws + off); off += (size_t)(VT_*1024)/2;
  // ---- coop-only extension ----
  size_t coop_base = off;
  float* WheT = ws + off; off += (size_t)G_*U_;             // 4194304
  float* WdT  = ws + off; off += (size_t)G_*2048;           // 8388608
  float* WaT  = ws + off; off += (size_t)U_*2048;           // 2097152
  float* hdec = ws + off; off += (size_t)TD_*B_*U_;         // 2064384
  float* ctxb = ws + off; off += (size_t)TD_*B_*U_;         // 2064384
  unsigned* bar = (unsigned*)(ws + off); off += 2048;
  size_t need_bytes = off * sizeof(float);
  (void)coop_base;

  bool coop_ok = (need_bytes <= ws_size);

  // zero attn slot0 + cst (both paths)
  zero_kernel<<<32, 256, 0, stream>>>((float4*)attn_buf, (B_*U_)/4);
  zero_kernel<<<32, 256, 0, stream>>>((float4*)cst, (B_*U_)/4);

  // input pre-activations + Wf transpose (off the critical recurrence)
  gemm_rows<<<dim3(G_/256, (TS_*B_)/16), 256, 0, stream>>>(enc_emb, enc_in, TS_, Wx_e, b_e, Xe, G_, E_);
  gemm_rows<<<dim3(G_/256, (TD_*B_)/16), 256, 0, stream>>>(dec_emb, dec_in, TD_, Wx_d, b_d, Xd, G_, E_);
  transpose_f2bf<<<dim3(VT_/32, 1024/32), 256, 0, stream>>>(Wf, WfT);

  const float* Wxa = Wx_d + (size_t)E_*G_;

  if(coop_ok){
    // barrier region + weight transposes
    zero_kernel<<<2, 256, 0, stream>>>((float4*)bar, 2048/4);
    transpose_f32<<<dim3(128, 32), 256, 0, stream>>>(Wh_e, WheT, G_, U_, 0);
    transpose_f32<<<dim3(128, 32), 256, 0, stream>>>(Wh_d, WdT, G_, 2048, 0);
    transpose_f32<<<dim3(128, 32), 256, 0, stream>>>(Wxa,  WdT, G_, 2048, U_);
    transpose_f32<<<dim3(32, 64),  256, 0, stream>>>(Wa,   WaT, U_, 2048, 0);

    EncP ep;
    ep.WheT = WheT; ep.Xe = Xe; ep.zeros = attn_buf;
    ep.memory = memory; ep.cst = cst; ep.bar = bar;
    void* ea[1] = { (void*)&ep };
    hipError_t e1 = hipLaunchCooperativeKernel(enc_rnn, dim3(NB_), dim3(256), ea, 0u, stream);
    if(e1 != hipSuccess) coop_ok = false;

    if(coop_ok){
      gemm_rows<<<dim3(U_/256, (TS_*B_)/16), 256, 0, stream>>>(memory, nullptr, 0, Wm, nullptr, keys, U_, U_);
      DecP dp;
      dp.WdT = WdT; dp.WaT = WaT; dp.Xd = Xd;
      dp.keys = keys; dp.memory = memory; dp.h_enc = memory + (size_t)(TS_-1)*B_*U_;
      dp.hdec = hdec; dp.ctxb = ctxb; dp.attn = attn_buf; dp.cst = cst;
      dp.attn_bf = attn_bf; dp.bar = bar + 128;   // fresh counters (zeroed region)
      void* da[1] = { (void*)&dp };
      hipError_t e2 = hipLaunchCooperativeKernel(dec_rnn, dim3(NB_), dim3(256), da, 0u, stream);
      if(e2 != hipSuccess) coop_ok = false;
    }
  }

  if(!coop_ok){
    // -------- fallback: verified multi-launch sequence --------
    zero_kernel<<<32, 256, 0, stream>>>((float4*)attn_buf, (B_*U_)/4);
    zero_kernel<<<32, 256, 0, stream>>>((float4*)cst, (B_*U_)/4);
    for(int t=0; t<TS_; t++){
      const float* hprev = (t==0) ? attn_buf : memory + (size_t)(t-1)*B_*U_;
      step_mm<<<dim3(G_/64, 8), 256, 0, stream>>>(Wh_e, Wh_e, hprev, hprev, zpart, G_, 8);
      gate_h<<<128, 256, 0, stream>>>(Xe + (size_t)t*B_*G_, zpart, 8, cst,
                                      memory + (size_t)t*B_*U_);
    }
    gemm_rows<<<dim3(U_/256, (TS_*B_)/16), 256, 0, stream>>>(memory, nullptr, 0, Wm, nullptr, keys, U_, U_);
    const float* mem_last = memory + (size_t)(TS_-1)*B_*U_;
    const float* Wa2 = Wa + (size_t)U_*U_;
    for(int t=0; t<TD_; t++){
      const float* hin   = (t==0) ? mem_last : hbuf;
      const float* aprev = attn_buf + (size_t)t*B_*U_;
      float* anext       = attn_buf + (size_t)(t+1)*B_*U_;
      step_mm<<<dim3(G_/64, 16), 256, 0, stream>>>(Wh_d, Wxa, hin, aprev, zpart, G_, 8);
      dec_gate_attn<<<B_, 256, 0, stream>>>(Xd + (size_t)t*B_*G_, zpart, cst,
                                            keys, memory, hbuf, ctxs);
      step_mm<<<dim3(U_/64, 16), 256, 0, stream>>>(Wa, Wa2, hbuf, ctxs, apart, U_, 8);
      attn_combine<<<128, 256, 0, stream>>>(apart, anext, attn_bf + (size_t)t*B_*U_);
    }
  }

  // logits = attn_all @ Wf + bf  (bf16 MFMA)
  logits_gemm<<<dim3((TD_*B_)/32, VT_/256), 256, 0, stream>>>(attn_bf, WfT, bf, out);
}